// Round 1
// baseline (123.071 us; speedup 1.0000x reference)
//
#include <hip/hip_runtime.h>
#include <math.h>

// Problem constants (from reference): IMG_SIZE=1024, B=64, G=128, A=3, N=1280
#define NBOX   1280
#define BVAL   64
#define GVAL   128
#define NFLOAT (BVAL * GVAL * GVAL * 15)   // 15,728,640 floats = 62.9 MB
#define NVEC   (NFLOAT / 4)                // 3,932,160 float4

__device__ __forceinline__ float softplus_f(float z) {
    // softplus(z) = max(z,0) + log1p(exp(-|z|)); stable, fast-math intrinsics
    return fmaxf(z, 0.f) + __logf(1.f + __expf(-fabsf(z)));
}

// Single fused kernel:
//   block 0         : per-box target build + dedup (last-write-wins) + gather-adjust
//   blocks 1..N-1   : grid-stride float4 sweep of y_pred summing 0.5*softplus(conf)
__global__ void __launch_bounds__(256) yolo_loss_kernel(
    const float* __restrict__ yp,
    const float* __restrict__ gbox,
    const float* __restrict__ anch,
    const int*   __restrict__ bidx,
    float*       __restrict__ out)
{
    __shared__ int   skey[NBOX];
    __shared__ int   sb[NBOX];
    __shared__ float sv[NBOX][4];
    __shared__ float swave[4];

    const int t = threadIdx.x;
    float acc = 0.f;

    if (blockIdx.x == 0) {
        // ---- phase 1: per-box key + target values ----
        for (int n = t; n < NBOX; n += 256) {
            float gx = gbox[n * 4 + 0] * 0.125f;   // stride = 8
            float gy = gbox[n * 4 + 1] * 0.125f;
            float gw = gbox[n * 4 + 2] * 0.125f;
            float gh = gbox[n * 4 + 3] * 0.125f;
            int gi = (int)gx, gj = (int)gy;
            int best = 0; float bestr = -1.f, baw = 1.f, bah = 1.f;
            #pragma unroll
            for (int a = 0; a < 3; a++) {
                float aw = anch[a * 2 + 0] * 0.125f;
                float ah = anch[a * 2 + 1] * 0.125f;
                float inter = fminf(aw, gw) * fminf(ah, gh);
                float uni   = aw * ah + gw * gh - inter;
                float r     = inter / uni;
                if (r > bestr) { bestr = r; best = a; baw = aw; bah = ah; }  // first-wins ties like argmax
            }
            int b = bidx[n];
            skey[n]  = ((b * 3 + best) * 128 + gj) * 128 + gi;
            sb[n]    = b;
            sv[n][0] = gx - (float)gi;
            sv[n][1] = gy - (float)gj;
            sv[n][2] = __logf(gw / baw);
            sv[n][3] = __logf(gh / bah);
        }
        __syncthreads();
        // ---- phase 2: dedup (batch_idx sorted -> scan same-batch suffix; last write wins) ----
        for (int n = t; n < NBOX; n += 256) {
            int key = skey[n], b = sb[n];
            bool winner = true;
            for (int m2 = n + 1; m2 < NBOX; m2++) {
                if (sb[m2] != b) break;
                if (skey[m2] == key) { winner = false; break; }
            }
            if (winner) {
                int gi = key & 127;
                int gj = (key >> 7) & 127;
                int ba = key >> 14;          // b*3 + best
                int best = ba % 3;
                int b2   = ba / 3;
                long base = ((((long)b2 * GVAL + gj) * GVAL) + gi) * 15 + best * 5;
                float conf = yp[base + 0];
                float px = 1.f / (1.f + __expf(-yp[base + 1]));
                float py = 1.f / (1.f + __expf(-yp[base + 2]));
                float pw = yp[base + 3];
                float ph = yp[base + 4];
                float dx = px - sv[n][0];
                float dy = py - sv[n][1];
                float dw = pw - sv[n][2];
                float dh = ph - sv[n][3];
                float lp = __logf(1.f + __expf(-fabsf(conf)));
                float sp_pos = fmaxf( conf, 0.f) + lp;   // softplus(conf)
                float sp_neg = fmaxf(-conf, 0.f) + lp;   // softplus(-conf)
                // coord + obj terms, minus the noobj term the sweep blocks over-counted
                acc += 5.f * (dx * dx + dy * dy + dw * dw + dh * dh)
                     + sp_neg - 0.5f * sp_pos;
            }
        }
    } else {
        // ---- noobj sweep: 0.5 * sum softplus(conf) over ALL cells ----
        const float4* yp4 = (const float4*)yp;
        int idx    = (blockIdx.x - 1) * 256 + t;
        int stride = (gridDim.x - 1) * 256;
        float lacc = 0.f;
        for (int v = idx; v < NVEC; v += stride) {
            float4 d = yp4[v];
            int r = (v * 4) % 15;                 // channel of first component
            float vals[4] = {d.x, d.y, d.z, d.w};
            #pragma unroll
            for (int k = 0; k < 4; k++) {
                int rr = r + k; if (rr >= 15) rr -= 15;
                if ((0x421u >> rr) & 1u)          // conf channels {0,5,10}
                    lacc += softplus_f(vals[k]);
            }
        }
        acc = 0.5f * lacc;
    }

    // ---- block reduction: wave shuffle -> LDS -> one atomic per block ----
    #pragma unroll
    for (int off = 32; off > 0; off >>= 1) acc += __shfl_down(acc, off, 64);
    int lane = t & 63, wid = t >> 6;
    if (lane == 0) swave[wid] = acc;
    __syncthreads();
    if (t == 0) {
        float s = swave[0] + swave[1] + swave[2] + swave[3];
        atomicAdd(out, s);
    }
}

extern "C" void kernel_launch(void* const* d_in, const int* in_sizes, int n_in,
                              void* d_out, int out_size, void* d_ws, size_t ws_size,
                              hipStream_t stream) {
    const float* yp   = (const float*)d_in[0];   // y_pred (B,G,G,15) fp32
    const float* gbox = (const float*)d_in[1];   // ground_bboxes (N,4) fp32
    const float* anch = (const float*)d_in[2];   // anchors (3,2) fp32
    const int*   bidx = (const int*)d_in[3];     // batch_idx (N,) int32
    float* out = (float*)d_out;

    // d_out is poisoned (0xAA) before every timed replay -> zero it ourselves
    hipMemsetAsync(out, 0, sizeof(float), stream);

    // 1 box block + 2047 sweep blocks (8 blocks/CU, memory-bound sweep)
    yolo_loss_kernel<<<dim3(2048), dim3(256), 0, stream>>>(yp, gbox, anch, bidx, out);
}